// Round 1
// baseline (211.150 us; speedup 1.0000x reference)
//
#include <hip/hip_runtime.h>

typedef _Float16 half8  __attribute__((ext_vector_type(8)));
typedef _Float16 half4v __attribute__((ext_vector_type(4)));
typedef _Float16 half2v __attribute__((ext_vector_type(2)));
typedef float    f32x4  __attribute__((ext_vector_type(4)));

__device__ __forceinline__ int swz(int row) {
    return ((row ^ (row >> 3)) & 15) << 4;   // XOR bits 4-7: 16B-granule swizzle, b128-safe
}

// One workgroup = one (b,h,n) 128x128 attention block. 8 waves, wave w owns q-rows [16w,16w+16).
// LDS: [0,32K) K fp16 [128][128] swizzled (later overlaid by P: 8 waves x [16][128] fp16)
//      [32K,64K) Vt fp16 [128][128] = V^T, swizzled.
__global__ __launch_bounds__(512, 4) void battn_kernel(
    const float* __restrict__ Q, const float* __restrict__ K,
    const float* __restrict__ V, float* __restrict__ O)
{
    extern __shared__ __align__(16) char smem[];
    const int tid  = threadIdx.x;
    const int lane = tid & 63;
    const int w    = tid >> 6;
    const int la   = lane & 15;
    const int u    = lane >> 4;
    const size_t base = (size_t)blockIdx.x * (128 * 128);

    const float* Qb = Q + base;
    const float* Kb = K + base;
    const float* Vb = V + base;
    float*       Ob = O + base;

    // ---------------- staging: issue all global loads first (MLP) ----------------
    float4 kreg[8];
#pragma unroll
    for (int it = 0; it < 8; ++it) {
        const int idx = it * 2048 + tid * 4;       // float index; row = idx>>7, col = idx&127
        kreg[it] = *(const float4*)(Kb + idx);
    }
    float4 vreg[2][4];                              // 2x8 tiles: rows j0,j0+1 x cols d0..d0+7
#pragma unroll
    for (int it = 0; it < 2; ++it) {
        const int tau = it * 512 + tid;
        const int d0 = (tau & 15) * 8;
        const int j0 = (tau >> 4) * 2;
        vreg[it][0] = *(const float4*)(Vb + j0 * 128 + d0);
        vreg[it][1] = *(const float4*)(Vb + j0 * 128 + d0 + 4);
        vreg[it][2] = *(const float4*)(Vb + (j0 + 1) * 128 + d0);
        vreg[it][3] = *(const float4*)(Vb + (j0 + 1) * 128 + d0 + 4);
    }
    // Q A-fragments straight to registers: A[m][k], m=lane&15, k=kk*32+u*8+i
    half8 qfrag[4];
    {
        const float* qrow = Qb + (w * 16 + la) * 128;
#pragma unroll
        for (int kk = 0; kk < 4; ++kk) {
            const float4 a = *(const float4*)(qrow + kk * 32 + u * 8);
            const float4 b = *(const float4*)(qrow + kk * 32 + u * 8 + 4);
            qfrag[kk][0] = (_Float16)a.x; qfrag[kk][1] = (_Float16)a.y;
            qfrag[kk][2] = (_Float16)a.z; qfrag[kk][3] = (_Float16)a.w;
            qfrag[kk][4] = (_Float16)b.x; qfrag[kk][5] = (_Float16)b.y;
            qfrag[kk][6] = (_Float16)b.z; qfrag[kk][7] = (_Float16)b.w;
        }
    }
    // K -> LDS fp16 row-major swizzled
#pragma unroll
    for (int it = 0; it < 8; ++it) {
        const int idx = it * 2048 + tid * 4;
        const int row = idx >> 7;
        const int col = idx & 127;
        half4v h;
        h[0] = (_Float16)kreg[it].x; h[1] = (_Float16)kreg[it].y;
        h[2] = (_Float16)kreg[it].z; h[3] = (_Float16)kreg[it].w;
        int byte = row * 256 + col * 2;
        byte ^= swz(row);
        *(half4v*)(smem + byte) = h;
    }
    // V -> LDS transposed (Vt[d][j]) swizzled; b32 writes, conflict-free via swz(row>>3 term)
#pragma unroll
    for (int it = 0; it < 2; ++it) {
        const int tau = it * 512 + tid;
        const int d0 = (tau & 15) * 8;
        const int j0 = (tau >> 4) * 2;
        const float r0[8] = {vreg[it][0].x, vreg[it][0].y, vreg[it][0].z, vreg[it][0].w,
                             vreg[it][1].x, vreg[it][1].y, vreg[it][1].z, vreg[it][1].w};
        const float r1[8] = {vreg[it][2].x, vreg[it][2].y, vreg[it][2].z, vreg[it][2].w,
                             vreg[it][3].x, vreg[it][3].y, vreg[it][3].z, vreg[it][3].w};
#pragma unroll
        for (int i = 0; i < 8; ++i) {
            half2v h;
            h[0] = (_Float16)r0[i];
            h[1] = (_Float16)r1[i];
            const int row = d0 + i;                 // Vt row = d
            int byte = 32768 + row * 256 + j0 * 2;
            byte ^= swz(row);
            *(half2v*)(smem + byte) = h;
        }
    }
    __syncthreads();

    // ---------------- S = Q K^T : A=Q(frag), B=K rows (B[k][n], n=lane&15) ----------------
    f32x4 acc[8];
#pragma unroll
    for (int t = 0; t < 8; ++t) acc[t] = (f32x4){0.f, 0.f, 0.f, 0.f};
#pragma unroll
    for (int t = 0; t < 8; ++t) {
#pragma unroll
        for (int kk = 0; kk < 4; ++kk) {
            const int row = t * 16 + la;            // K row = score col
            int byte = row * 256 + kk * 64 + u * 16;
            byte ^= swz(row);
            const half8 kf = *(const half8*)(smem + byte);
            acc[t] = __builtin_amdgcn_mfma_f32_16x16x32_f16(qfrag[kk], kf, acc[t], 0, 0, 0);
        }
    }
    // acc[t][r] = S[q-sub-row = 4u+r][col = 16t+la]

    // ---------------- row softmax (reduce over 16 lanes sharing u, and over t) -----------
    float inv[4];
#pragma unroll
    for (int r = 0; r < 4; ++r) {
        float m = acc[0][r];
#pragma unroll
        for (int t = 1; t < 8; ++t) m = fmaxf(m, acc[t][r]);
        m = fmaxf(m, __shfl_xor(m, 1));
        m = fmaxf(m, __shfl_xor(m, 2));
        m = fmaxf(m, __shfl_xor(m, 4));
        m = fmaxf(m, __shfl_xor(m, 8));
        float s = 0.f;
#pragma unroll
        for (int t = 0; t < 8; ++t) {
            const float e = __expf(acc[t][r] - m);
            acc[t][r] = e;
            s += e;
        }
        s += __shfl_xor(s, 1);
        s += __shfl_xor(s, 2);
        s += __shfl_xor(s, 4);
        s += __shfl_xor(s, 8);
        inv[r] = 1.0f / s;
    }

    __syncthreads();   // all waves done reading K before P overlays the K region

    // ---------------- P -> LDS fp16 (row-major per wave, swizzled) ----------------
#pragma unroll
    for (int t = 0; t < 8; ++t) {
#pragma unroll
        for (int r = 0; r < 4; ++r) {
            const int row = u * 4 + r;              // wave-local q row
            const int col = t * 16 + la;
            int byte = w * 4096 + row * 256 + col * 2;
            byte ^= swz(row);
            *(_Float16*)(smem + byte) = (_Float16)(acc[t][r] * inv[r]);
        }
    }
    __syncthreads();

    // ---------------- O^T = Vt * P^T : A=Vt rows (m=d), B=P rows (n=q) ----------------
    half8 pb[4];
#pragma unroll
    for (int kk = 0; kk < 4; ++kk) {
        int byte = w * 4096 + la * 256 + kk * 64 + u * 16;
        byte ^= swz(la);
        pb[kk] = *(const half8*)(smem + byte);
    }
    f32x4 oacc[8];
#pragma unroll
    for (int tt = 0; tt < 8; ++tt) oacc[tt] = (f32x4){0.f, 0.f, 0.f, 0.f};
#pragma unroll
    for (int tt = 0; tt < 8; ++tt) {
#pragma unroll
        for (int kk = 0; kk < 4; ++kk) {
            const int row = tt * 16 + la;           // Vt row = d
            int byte = 32768 + row * 256 + kk * 64 + u * 16;
            byte ^= swz(row);
            const half8 vf = *(const half8*)(smem + byte);
            oacc[tt] = __builtin_amdgcn_mfma_f32_16x16x32_f16(vf, pb[kk], oacc[tt], 0, 0, 0);
        }
    }
    // oacc[tt][r] = O[q = w*16+la][d = tt*16 + 4u + r] -> float4 coalesced store
#pragma unroll
    for (int tt = 0; tt < 8; ++tt) {
        const float4 ov = make_float4(oacc[tt][0], oacc[tt][1], oacc[tt][2], oacc[tt][3]);
        *(float4*)(Ob + (w * 16 + la) * 128 + tt * 16 + u * 4) = ov;
    }
}

extern "C" void kernel_launch(void* const* d_in, const int* in_sizes, int n_in,
                              void* d_out, int out_size, void* d_ws, size_t ws_size,
                              hipStream_t stream) {
    const float* q = (const float*)d_in[0];
    const float* k = (const float*)d_in[1];
    const float* v = (const float*)d_in[2];
    float* o = (float*)d_out;
    const int nblocks = in_sizes[0] / (128 * 128);   // 8*16*32 = 4096
    battn_kernel<<<dim3(nblocks), dim3(512), 65536, stream>>>(q, k, v, o);
}